// Round 4
// baseline (791.011 us; speedup 1.0000x reference)
//
#include <hip/hip_runtime.h>
#include <stdint.h>

typedef unsigned short u16;
typedef unsigned int u32;

// ---------------- constants ----------------
#define BATCH 2
#define NSEQ  4096
#define DIM   1024
#define HEADS 16
#define DH    64
#define WIN   512
#define INNER 2730
#define ROWS  8192
#define QKV_N 3072
#define FF1_N 5460
#define FF1_NP 5504      // padded N for ff1 (43*128)
#define INNER_P 2752     // padded K for ff2 (86*32)

typedef __attribute__((ext_vector_type(8))) short short8;
typedef __attribute__((ext_vector_type(4))) float float4v;

__device__ __forceinline__ float bf2f(u16 u){ union{u32 i;float f;}c; c.i=((u32)u)<<16; return c.f; }
__device__ __forceinline__ u16 f2bf(float f){ union{float f;u32 i;}c; c.f=f; u32 i=c.i;
    return (u16)((i + 0x7FFFu + ((i>>16)&1u))>>16); }

// async global->LDS, 16B per lane. lds ptr must be wave-uniform base; HW places lane i at base+i*16.
__device__ __forceinline__ void gl_lds16(const u16* g, const u16* ldsbase) {
    __builtin_amdgcn_global_load_lds(
        (const __attribute__((address_space(1))) u32*)(uintptr_t)g,
        (__attribute__((address_space(3))) u32*)(uintptr_t)ldsbase,
        16, 0, 0);
}

// ---------------- weight transpose + cast: wt[n][k] = bf16(w[k][n]), zero-padded ----------------
__global__ __launch_bounds__(256) void wtrans_kernel(const float* __restrict__ w, u16* __restrict__ wt,
                                                     int K0, int N0, int K1, int N1) {
    __shared__ float tile[32][33];
    int kt = blockIdx.x, nt = blockIdx.y;
    int tx = threadIdx.x & 31, ty = threadIdx.x >> 5;   // ty 0..7
#pragma unroll
    for (int yy = 0; yy < 4; yy++) {
        int k = kt*32 + ty + yy*8, n = nt*32 + tx;
        tile[ty+yy*8][tx] = (k < K0 && n < N0) ? w[(size_t)k*N0 + n] : 0.f;
    }
    __syncthreads();
#pragma unroll
    for (int yy = 0; yy < 4; yy++) {
        int n = nt*32 + ty + yy*8, k = kt*32 + tx;
        if (n < N1 && k < K1) wt[(size_t)n*K1 + k] = f2bf(tile[tx][ty+yy*8]);
    }
}

// ---------------- LayerNorm: fp32 in, bf16 out (dim = 1024) ----------------
__global__ __launch_bounds__(256) void ln_kernel(const float* __restrict__ x,
                                                 const float* __restrict__ w,
                                                 const float* __restrict__ b,
                                                 u16* __restrict__ out) {
    int row = blockIdx.x;
    const float* xr = x + (size_t)row * DIM;
    int t = threadIdx.x;
    float v[4];
    float s = 0.f, s2 = 0.f;
#pragma unroll
    for (int i = 0; i < 4; i++) {
        float f = xr[t + 256 * i];
        v[i] = f; s += f; s2 += f * f;
    }
#pragma unroll
    for (int off = 32; off; off >>= 1) { s += __shfl_xor(s, off); s2 += __shfl_xor(s2, off); }
    __shared__ float ls[10];
    int wave = t >> 6, lane = t & 63;
    if (lane == 0) { ls[wave] = s; ls[4 + wave] = s2; }
    __syncthreads();
    if (t == 0) {
        float ts  = ls[0] + ls[1] + ls[2] + ls[3];
        float ts2 = ls[4] + ls[5] + ls[6] + ls[7];
        float mean = ts * (1.f / DIM);
        float var  = ts2 * (1.f / DIM) - mean * mean;
        ls[8] = mean; ls[9] = 1.f / sqrtf(var + 1e-5f);
    }
    __syncthreads();
    float mean = ls[8], inv = ls[9];
    u16* orow = out + (size_t)row * DIM;
#pragma unroll
    for (int i = 0; i < 4; i++) {
        int c = t + 256 * i;
        float y = (v[i] - mean) * inv * w[c];
        if (b) y += b[c];
        orow[c] = f2bf(y);
    }
}

// ---------------- m97-style GEMM: C[M,N] = A[M,K] @ Bt[N,K]^T (+fp32 resid) ----------------
template <bool F32OUT>
__global__ __launch_bounds__(256) void gemm_tile(const u16* __restrict__ A,
                                                 const u16* __restrict__ Bt,
                                                 const float* __restrict__ resid,
                                                 void* __restrict__ Cv,
                                                 int M, int N, int K) {
    __shared__ u16 As[128 * 32];   // [m][k] row-major, rows of 64B
    __shared__ u16 Bs[128 * 32];   // [n][k] row-major
    int tiles_n = N >> 7;
    int tm = blockIdx.x / tiles_n, tn = blockIdx.x % tiles_n;
    int tid = threadIdx.x, wave = tid >> 6, lane = tid & 63;
    int quad = lane >> 4, l15 = lane & 15;
    int wm = wave >> 1, wn = wave & 1;
    int srow = wave * 32 + (lane >> 2);        // staging row
    int scol = (lane & 3) * 8;                 // staging col (halves)
    const u16* Ag = A  + (size_t)(tm * 128 + srow) * K + scol;
    const u16* Bg = Bt + (size_t)(tn * 128 + srow) * K + scol;
    const u16* Alb = &As[wave * 1024];         // wave-uniform LDS bases
    const u16* Blb = &Bs[wave * 1024];
    float4v acc[4][4];
#pragma unroll
    for (int i = 0; i < 4; i++)
#pragma unroll
        for (int j = 0; j < 4; j++) acc[i][j] = (float4v){0.f, 0.f, 0.f, 0.f};
    for (int k0 = 0; k0 < K; k0 += 32) {
        __syncthreads();
        gl_lds16(Ag + k0,                 Alb);
        gl_lds16(Ag + (size_t)16*K + k0,  Alb + 512);
        gl_lds16(Bg + k0,                 Blb);
        gl_lds16(Bg + (size_t)16*K + k0,  Blb + 512);
        __syncthreads();
        short8 af[4], bf[4];
#pragma unroll
        for (int i = 0; i < 4; i++) af[i] = *(const short8*)&As[(wm*64 + i*16 + l15)*32 + quad*8];
#pragma unroll
        for (int j = 0; j < 4; j++) bf[j] = *(const short8*)&Bs[(wn*64 + j*16 + l15)*32 + quad*8];
#pragma unroll
        for (int i = 0; i < 4; i++)
#pragma unroll
            for (int j = 0; j < 4; j++)
                acc[i][j] = __builtin_amdgcn_mfma_f32_16x16x32_bf16(af[i], bf[j], acc[i][j], 0, 0, 0);
    }
#pragma unroll
    for (int i = 0; i < 4; i++) {
#pragma unroll
        for (int r = 0; r < 4; r++) {
            size_t row = (size_t)(tm*128 + wm*64 + i*16 + quad*4 + r);
#pragma unroll
            for (int j = 0; j < 4; j++) {
                int col = tn*128 + wn*64 + j*16 + l15;
                size_t idx = row * N + col;
                float v = acc[i][j][r];
                if (F32OUT) { if (resid) v += resid[idx]; ((float*)Cv)[idx] = v; }
                else ((u16*)Cv)[idx] = f2bf(v);
            }
        }
    }
}

// ---------------- rotary (in-place on bf16 qkv) + q scale ----------------
__global__ __launch_bounds__(256) void rotary_kernel(u16* __restrict__ qkv) {
    int idx = blockIdx.x * 256 + threadIdx.x;       // B*N*H*32
    int i  = idx & 31;
    int hh = (idx >> 5) & 15;
    int n  = (idx >> 9) & (NSEQ - 1);
    int b  = idx >> 21;
    float inv = expf(-(float)i * 0.28782313663f);   // ln(10000)/32
    float f = (float)n * inv;
    float sn, cs;
    sincosf(f, &sn, &cs);
    size_t base = ((size_t)(b * NSEQ + n)) * QKV_N;
    size_t iq = base + hh * 64 + i;
    float q0 = bf2f(qkv[iq]), q1 = bf2f(qkv[iq + 32]);
    qkv[iq]      = f2bf((q0 * cs - q1 * sn) * 0.125f);
    qkv[iq + 32] = f2bf((q1 * cs + q0 * sn) * 0.125f);
    size_t ik = base + DIM + hh * 64 + i;
    float k0 = bf2f(qkv[ik]), k1 = bf2f(qkv[ik + 32]);
    qkv[ik]      = f2bf(k0 * cs - k1 * sn);
    qkv[ik + 32] = f2bf(k1 * cs + k0 * sn);
}

// ---------------- V transpose: vt[b][h][d][n] = qkv.v[b,n,h,d] ----------------
__global__ __launch_bounds__(256) void vtrans_kernel(const u16* __restrict__ qkv, u16* __restrict__ vt) {
    __shared__ u16 tile[64][72];
    int t = threadIdx.x;
    int n0 = (blockIdx.x & 63) * 64;
    int hh = (blockIdx.x >> 6) & 15;
    int b  = blockIdx.x >> 10;
    int r = t >> 2, cb = (t & 3) * 16;
    const u16* src = qkv + (size_t)(b * NSEQ + n0 + r) * QKV_N + 2 * DIM + hh * 64 + cb;
    uint4 v0 = *(const uint4*)(src);
    uint4 v1 = *(const uint4*)(src + 8);
    *(uint4*)&tile[r][cb]     = v0;
    *(uint4*)&tile[r][cb + 8] = v1;
    __syncthreads();
    int d = t >> 2, nb = (t & 3) * 16;
    __align__(16) u16 vals[16];
#pragma unroll
    for (int e = 0; e < 16; e++) vals[e] = tile[nb + e][d];
    u16* dst = vt + ((size_t)(b * HEADS + hh) * DH + d) * NSEQ + n0 + nb;
    *(uint4*)(dst)     = *(uint4*)&vals[0];
    *(uint4*)(dst + 8) = *(uint4*)&vals[8];
}

// ---------------- MFMA flash attention, S-transposed formulation ----------------
// One wave per 16 queries. S^T = K·Q^T (col=q, row=key): per-lane softmax state,
// 128-key chunks, packed LDS P tile, PV as O^T = V^T·P^T.
__global__ __launch_bounds__(256) void attn_kernel(const u16* __restrict__ qkv,
                                                   const u16* __restrict__ vt,
                                                   u16* __restrict__ o) {
    __shared__ u16 p_lds[4][16][136];              // per-wave P tile [q][key], stride 272B
    int tid = threadIdx.x, wave = tid >> 6, lane = tid & 63;
    int quad = lane >> 4, l15 = lane & 15;
    int bi = blockIdx.x;
    int bq = bi & 7, w0 = (bi >> 3) & 7, hh = (bi >> 6) & 15, b = bi >> 10;
    int qt = bq * 4 + wave;                        // q-tile 0..31 within window
    int qlocal = qt * 16 + l15;                    // this lane's query (within window)
    // Q as B-operand: B[k=d][n=q] -> per lane row l15 (q), 8 consecutive d
    const u16* qp = qkv + (size_t)(b*NSEQ + w0*WIN + qt*16 + l15) * QKV_N + hh*64 + quad*8;
    short8 bq0 = *(const short8*)(qp);
    short8 bq1 = *(const short8*)(qp + 32);
    int krow0 = b * NSEQ + (w0 - 1) * WIN;         // row of combined key 0
    const u16* vth = vt + ((size_t)(b * HEADS + hh) * DH) * NSEQ + (w0 - 1) * WIN;
    float m_ = -1e30f, l_ = 0.f;
    float4v O[4] = {{0,0,0,0},{0,0,0,0},{0,0,0,0},{0,0,0,0}};
    int cstart = (w0 == 0) ? 4 : 0;                // 128-key chunks; [0,512)=prev window
    int clast  = (527 + qt * 16) >> 7;
    u16 (*pt)[136] = p_lds[wave];
    for (int c = cstart; c <= clast; c++) {
        float4v s[8];
#pragma unroll
        for (int t = 0; t < 8; t++) {
            int kb = c * 128 + t * 16;
            // K as A-operand: A[m=key][k=d] -> per lane row kb+l15, 8 consecutive d
            const u16* kp = qkv + (size_t)(krow0 + kb + l15) * QKV_N + DIM + hh*64 + quad*8;
            short8 ka0 = *(const short8*)(kp);
            short8 ka1 = *(const short8*)(kp + 32);
            float4v st = {0.f, 0.f, 0.f, 0.f};
            st = __builtin_amdgcn_mfma_f32_16x16x32_bf16(ka0, bq0, st, 0, 0, 0);
            st = __builtin_amdgcn_mfma_f32_16x16x32_bf16(ka1, bq1, st, 0, 0, 0);
            int ck = kb + quad * 4;                // combined key of reg r = ck + r
#pragma unroll
            for (int r = 0; r < 4; r++)
                if (ck + r >= 512 && ck + r - 512 > qlocal) st[r] = -1e30f;
            s[t] = st;
        }
        // per-lane chunk max, reduce across the 4 quads holding this q
        float mc = -1e30f;
#pragma unroll
        for (int t = 0; t < 8; t++)
#pragma unroll
            for (int r = 0; r < 4; r++) mc = fmaxf(mc, s[t][r]);
        mc = fmaxf(mc, __shfl_xor(mc, 16));
        mc = fmaxf(mc, __shfl_xor(mc, 32));
        float mn = fmaxf(m_, mc);
        float alpha = __expf(m_ - mn);
        m_ = mn;
        float su = 0.f;
#pragma unroll
        for (int t = 0; t < 8; t++) {
            union { u16 h[4]; uint2 v; } pk;
#pragma unroll
            for (int r = 0; r < 4; r++) {
                float p = __expf(s[t][r] - mn);
                su += p;
                pk.h[r] = f2bf(p);
            }
            *(uint2*)&pt[l15][t*16 + quad*4] = pk.v;   // P[q][key], 4 packed keys
        }
        su += __shfl_xor(su, 16);
        su += __shfl_xor(su, 32);
        l_ = l_ * alpha + su;
#pragma unroll
        for (int t = 0; t < 4; t++)
#pragma unroll
            for (int r = 0; r < 4; r++) O[t][r] *= alpha;
        // PV: O^T = V^T · P^T ; A=V^T rows are vt rows, B=P^T reads P[q][key] b128
#pragma unroll
        for (int g = 0; g < 4; g++) {
            short8 pf = *(const short8*)&pt[l15][g*32 + quad*8];
            const u16* vp = vth + (size_t)l15 * NSEQ + c*128 + g*32 + quad*8;
#pragma unroll
            for (int t = 0; t < 4; t++) {
                short8 vf = *(const short8*)(vp + (size_t)(t*16) * NSEQ);
                O[t] = __builtin_amdgcn_mfma_f32_16x16x32_bf16(vf, pf, O[t], 0, 0, 0);
            }
        }
    }
    float inv = 1.f / l_;
    u16* op = o + (size_t)(b*NSEQ + w0*WIN + qt*16 + l15) * DIM + hh*64;
#pragma unroll
    for (int t = 0; t < 4; t++) {
        union { u16 h[4]; uint2 v; } pk;
#pragma unroll
        for (int r = 0; r < 4; r++) pk.h[r] = f2bf(O[t][r] * inv);
        *(uint2*)(op + t*16 + quad*4) = pk.v;      // d = t*16+quad*4+r consecutive
    }
}

// ---------------- GEGLU gate (padded strides) ----------------
__global__ __launch_bounds__(256) void geglu_kernel(const u16* __restrict__ u, u16* __restrict__ ag) {
    int col = blockIdx.x * 256 + threadIdx.x;
    int row = blockIdx.y;
    if (col >= INNER_P) return;
    float v = 0.f;
    if (col < INNER) {
        float a = bf2f(u[(size_t)row * FF1_NP + col]);
        float g = bf2f(u[(size_t)row * FF1_NP + INNER + col]);
        v = a * 0.5f * g * (1.f + erff(g * 0.70710678118f));
    }
    ag[(size_t)row * INNER_P + col] = f2bf(v);
}

// ---------------- launch ----------------
extern "C" void kernel_launch(void* const* d_in, const int* in_sizes, int n_in,
                              void* d_out, int out_size, void* d_ws, size_t ws_size,
                              hipStream_t stream) {
    const float* x      = (const float*)d_in[0];
    const float* ln1_w  = (const float*)d_in[1];
    const float* ln1_b  = (const float*)d_in[2];
    const float* w_qkv  = (const float*)d_in[3];
    const float* w_out  = (const float*)d_in[4];
    const float* ln2_w  = (const float*)d_in[5];
    const float* w_ff1  = (const float*)d_in[6];
    const float* w_ff2  = (const float*)d_in[7];
    float* out = (float*)d_out;

    char* ws = (char*)d_ws;
    size_t off = 0;
    auto alloc = [&](size_t bytes) { size_t o = off; off += (bytes + 255) & ~(size_t)255; return o; };
    size_t off_wqt  = alloc((size_t)QKV_N  * DIM * 2);
    size_t off_wot  = alloc((size_t)DIM    * DIM * 2);
    size_t off_wf1t = alloc((size_t)FF1_NP * DIM * 2);
    size_t off_wf2t = alloc((size_t)DIM    * INNER_P * 2);
    size_t off_h    = alloc((size_t)ROWS * DIM * 2);
    size_t sz_qkv = (size_t)ROWS * QKV_N * 2;
    size_t sz_vt  = (size_t)BATCH * HEADS * DH * NSEQ * 2;
    size_t sz_o   = (size_t)ROWS * DIM * 2;
    size_t sz_u   = (size_t)ROWS * FF1_NP * 2;
    size_t r1sz = sz_qkv + sz_vt + sz_o; if (sz_u > r1sz) r1sz = sz_u;
    size_t off_r1   = alloc(r1sz);
    size_t off_x1   = alloc((size_t)ROWS * DIM * 4);
    size_t off_ag   = alloc((size_t)ROWS * INNER_P * 2);

    u16* wqt  = (u16*)(ws + off_wqt);
    u16* wot  = (u16*)(ws + off_wot);
    u16* wf1t = (u16*)(ws + off_wf1t);
    u16* wf2t = (u16*)(ws + off_wf2t);
    u16* h    = (u16*)(ws + off_h);
    u16* qkv  = (u16*)(ws + off_r1);
    u16* vt   = (u16*)(ws + off_r1 + sz_qkv);
    u16* o    = (u16*)(ws + off_r1 + sz_qkv + sz_vt);
    u16* u    = (u16*)(ws + off_r1);
    float* x1 = (float*)(ws + off_x1);
    u16* ag   = (u16*)(ws + off_ag);

    // 0) transpose+cast weights -> bf16 [N][K] (zero-padded)
    wtrans_kernel<<<dim3(32, 96),  256, 0, stream>>>(w_qkv, wqt,  DIM,   QKV_N, DIM,     QKV_N);
    wtrans_kernel<<<dim3(32, 32),  256, 0, stream>>>(w_out, wot,  DIM,   DIM,   DIM,     DIM);
    wtrans_kernel<<<dim3(32, 172), 256, 0, stream>>>(w_ff1, wf1t, DIM,   FF1_N, DIM,     FF1_NP);
    wtrans_kernel<<<dim3(86, 32),  256, 0, stream>>>(w_ff2, wf2t, INNER, DIM,   INNER_P, DIM);

    // 1) LN1
    ln_kernel<<<ROWS, 256, 0, stream>>>(x, ln1_w, ln1_b, h);
    // 2) qkv = h @ w_qkv
    gemm_tile<false><<<(ROWS/128) * (QKV_N/128), 256, 0, stream>>>(h, wqt, nullptr, qkv, ROWS, QKV_N, DIM);
    // 3) rotary + q scale
    rotary_kernel<<<(BATCH * NSEQ * HEADS * 32) / 256, 256, 0, stream>>>(qkv);
    // 4) V transpose
    vtrans_kernel<<<BATCH * HEADS * (NSEQ / 64), 256, 0, stream>>>(qkv, vt);
    // 5) attention
    attn_kernel<<<BATCH * HEADS * 8 * 8, 256, 0, stream>>>(qkv, vt, o);
    // 6) x1 = o @ w_out + x
    gemm_tile<true><<<(ROWS/128) * (DIM/128), 256, 0, stream>>>(o, wot, x, x1, ROWS, DIM, DIM);
    // 7) h2 = LN2(x1)
    ln_kernel<<<ROWS, 256, 0, stream>>>(x1, ln2_w, nullptr, h);
    // 8) u = h2 @ w_ff1 (N padded to 5504)
    gemm_tile<false><<<(ROWS/128) * (FF1_NP/128), 256, 0, stream>>>(h, wf1t, nullptr, u, ROWS, FF1_NP, DIM);
    // 9) ag = a * gelu(g) (K padded to 2752, zero-filled)
    geglu_kernel<<<dim3((INNER_P + 255) / 256, ROWS), 256, 0, stream>>>(u, ag);
    // 10) out = ag @ w_ff2 + x1
    gemm_tile<true><<<(ROWS/128) * (DIM/128), 256, 0, stream>>>(ag, wf2t, x1, out, ROWS, DIM, INNER_P);

    (void)in_sizes; (void)n_in; (void)out_size; (void)ws_size;
}

// Round 5
// 647.648 us; speedup vs baseline: 1.2214x; 1.2214x over previous
//
#include <hip/hip_runtime.h>
#include <stdint.h>

typedef unsigned short u16;
typedef unsigned int u32;

// ---------------- constants ----------------
#define BATCH 2
#define NSEQ  4096
#define DIM   1024
#define HEADS 16
#define DH    64
#define WIN   512
#define INNER 2730
#define ROWS  8192
#define QKV_N 3072
#define FF1_N 5460
#define FF1_NP 5504      // padded N for ff1 (43*128)
#define INNER_P 2752     // padded K for ff2 (86*32)

typedef __attribute__((ext_vector_type(8))) short short8;
typedef __attribute__((ext_vector_type(4))) float float4v;

__device__ __forceinline__ float bf2f(u16 u){ union{u32 i;float f;}c; c.i=((u32)u)<<16; return c.f; }
__device__ __forceinline__ u16 f2bf(float f){ union{float f;u32 i;}c; c.f=f; u32 i=c.i;
    return (u16)((i + 0x7FFFu + ((i>>16)&1u))>>16); }

// async global->LDS, 16B per lane. LDS dest = wave-uniform base + lane*16; global src may scatter per lane.
__device__ __forceinline__ void gl_lds16(const u16* g, const u16* ldsbase) {
    __builtin_amdgcn_global_load_lds(
        (const __attribute__((address_space(1))) u32*)(uintptr_t)g,
        (__attribute__((address_space(3))) u32*)(uintptr_t)ldsbase,
        16, 0, 0);
}

// ---------------- weight transpose + cast: wt[n][k] = bf16(w[k][n]), zero-padded ----------------
__global__ __launch_bounds__(256) void wtrans_kernel(const float* __restrict__ w, u16* __restrict__ wt,
                                                     int K0, int N0, int K1, int N1) {
    __shared__ float tile[32][33];
    int kt = blockIdx.x, nt = blockIdx.y;
    int tx = threadIdx.x & 31, ty = threadIdx.x >> 5;
#pragma unroll
    for (int yy = 0; yy < 4; yy++) {
        int k = kt*32 + ty + yy*8, n = nt*32 + tx;
        tile[ty+yy*8][tx] = (k < K0 && n < N0) ? w[(size_t)k*N0 + n] : 0.f;
    }
    __syncthreads();
#pragma unroll
    for (int yy = 0; yy < 4; yy++) {
        int n = nt*32 + ty + yy*8, k = kt*32 + tx;
        if (n < N1 && k < K1) wt[(size_t)n*K1 + k] = f2bf(tile[tx][ty+yy*8]);
    }
}

// ---------------- LayerNorm: fp32 in, bf16 out (dim = 1024) ----------------
__global__ __launch_bounds__(256) void ln_kernel(const float* __restrict__ x,
                                                 const float* __restrict__ w,
                                                 const float* __restrict__ b,
                                                 u16* __restrict__ out) {
    int row = blockIdx.x;
    const float* xr = x + (size_t)row * DIM;
    int t = threadIdx.x;
    float v[4];
    float s = 0.f, s2 = 0.f;
#pragma unroll
    for (int i = 0; i < 4; i++) {
        float f = xr[t + 256 * i];
        v[i] = f; s += f; s2 += f * f;
    }
#pragma unroll
    for (int off = 32; off; off >>= 1) { s += __shfl_xor(s, off); s2 += __shfl_xor(s2, off); }
    __shared__ float ls[10];
    int wave = t >> 6, lane = t & 63;
    if (lane == 0) { ls[wave] = s; ls[4 + wave] = s2; }
    __syncthreads();
    if (t == 0) {
        float ts  = ls[0] + ls[1] + ls[2] + ls[3];
        float ts2 = ls[4] + ls[5] + ls[6] + ls[7];
        float mean = ts * (1.f / DIM);
        float var  = ts2 * (1.f / DIM) - mean * mean;
        ls[8] = mean; ls[9] = 1.f / sqrtf(var + 1e-5f);
    }
    __syncthreads();
    float mean = ls[8], inv = ls[9];
    u16* orow = out + (size_t)row * DIM;
#pragma unroll
    for (int i = 0; i < 4; i++) {
        int c = t + 256 * i;
        float y = (v[i] - mean) * inv * w[c];
        if (b) y += b[c];
        orow[c] = f2bf(y);
    }
}

// ---------------- m97-style GEMM: C[M,N] = A[M,K] @ Bt[N,K]^T (+fp32 resid) ----------------
template <bool F32OUT>
__global__ __launch_bounds__(256) void gemm_tile(const u16* __restrict__ A,
                                                 const u16* __restrict__ Bt,
                                                 const float* __restrict__ resid,
                                                 void* __restrict__ Cv,
                                                 int M, int N, int K) {
    __shared__ u16 As[128 * 32];
    __shared__ u16 Bs[128 * 32];
    int tiles_n = N >> 7;
    int tm = blockIdx.x / tiles_n, tn = blockIdx.x % tiles_n;
    int tid = threadIdx.x, wave = tid >> 6, lane = tid & 63;
    int quad = lane >> 4, l15 = lane & 15;
    int wm = wave >> 1, wn = wave & 1;
    int srow = wave * 32 + (lane >> 2);
    int scol = (lane & 3) * 8;
    const u16* Ag = A  + (size_t)(tm * 128 + srow) * K + scol;
    const u16* Bg = Bt + (size_t)(tn * 128 + srow) * K + scol;
    const u16* Alb = &As[wave * 1024];
    const u16* Blb = &Bs[wave * 1024];
    float4v acc[4][4];
#pragma unroll
    for (int i = 0; i < 4; i++)
#pragma unroll
        for (int j = 0; j < 4; j++) acc[i][j] = (float4v){0.f, 0.f, 0.f, 0.f};
    for (int k0 = 0; k0 < K; k0 += 32) {
        __syncthreads();
        gl_lds16(Ag + k0,                 Alb);
        gl_lds16(Ag + (size_t)16*K + k0,  Alb + 512);
        gl_lds16(Bg + k0,                 Blb);
        gl_lds16(Bg + (size_t)16*K + k0,  Blb + 512);
        __syncthreads();
        short8 af[4], bf[4];
#pragma unroll
        for (int i = 0; i < 4; i++) af[i] = *(const short8*)&As[(wm*64 + i*16 + l15)*32 + quad*8];
#pragma unroll
        for (int j = 0; j < 4; j++) bf[j] = *(const short8*)&Bs[(wn*64 + j*16 + l15)*32 + quad*8];
#pragma unroll
        for (int i = 0; i < 4; i++)
#pragma unroll
            for (int j = 0; j < 4; j++)
                acc[i][j] = __builtin_amdgcn_mfma_f32_16x16x32_bf16(af[i], bf[j], acc[i][j], 0, 0, 0);
    }
#pragma unroll
    for (int i = 0; i < 4; i++) {
#pragma unroll
        for (int r = 0; r < 4; r++) {
            size_t row = (size_t)(tm*128 + wm*64 + i*16 + quad*4 + r);
#pragma unroll
            for (int j = 0; j < 4; j++) {
                int col = tn*128 + wn*64 + j*16 + l15;
                size_t idx = row * N + col;
                float v = acc[i][j][r];
                if (F32OUT) { if (resid) v += resid[idx]; ((float*)Cv)[idx] = v; }
                else ((u16*)Cv)[idx] = f2bf(v);
            }
        }
    }
}

// ---------------- rotary (in-place on bf16 qkv) + q scale ----------------
__global__ __launch_bounds__(256) void rotary_kernel(u16* __restrict__ qkv) {
    int idx = blockIdx.x * 256 + threadIdx.x;
    int i  = idx & 31;
    int hh = (idx >> 5) & 15;
    int n  = (idx >> 9) & (NSEQ - 1);
    int b  = idx >> 21;
    float inv = expf(-(float)i * 0.28782313663f);
    float f = (float)n * inv;
    float sn, cs;
    sincosf(f, &sn, &cs);
    size_t base = ((size_t)(b * NSEQ + n)) * QKV_N;
    size_t iq = base + hh * 64 + i;
    float q0 = bf2f(qkv[iq]), q1 = bf2f(qkv[iq + 32]);
    qkv[iq]      = f2bf((q0 * cs - q1 * sn) * 0.125f);
    qkv[iq + 32] = f2bf((q1 * cs + q0 * sn) * 0.125f);
    size_t ik = base + DIM + hh * 64 + i;
    float k0 = bf2f(qkv[ik]), k1 = bf2f(qkv[ik + 32]);
    qkv[ik]      = f2bf(k0 * cs - k1 * sn);
    qkv[ik + 32] = f2bf(k1 * cs + k0 * sn);
}

// ---------------- V transpose: vt[b][h][d][n] = qkv.v[b,n,h,d] ----------------
__global__ __launch_bounds__(256) void vtrans_kernel(const u16* __restrict__ qkv, u16* __restrict__ vt) {
    __shared__ u16 tile[64][72];
    int t = threadIdx.x;
    int n0 = (blockIdx.x & 63) * 64;
    int hh = (blockIdx.x >> 6) & 15;
    int b  = blockIdx.x >> 10;
    int r = t >> 2, cb = (t & 3) * 16;
    const u16* src = qkv + (size_t)(b * NSEQ + n0 + r) * QKV_N + 2 * DIM + hh * 64 + cb;
    uint4 v0 = *(const uint4*)(src);
    uint4 v1 = *(const uint4*)(src + 8);
    *(uint4*)&tile[r][cb]     = v0;
    *(uint4*)&tile[r][cb + 8] = v1;
    __syncthreads();
    int d = t >> 2, nb = (t & 3) * 16;
    __align__(16) u16 vals[16];
#pragma unroll
    for (int e = 0; e < 16; e++) vals[e] = tile[nb + e][d];
    u16* dst = vt + ((size_t)(b * HEADS + hh) * DH + d) * NSEQ + n0 + nb;
    *(uint4*)(dst)     = *(uint4*)&vals[0];
    *(uint4*)(dst + 8) = *(uint4*)&vals[8];
}

// ---------------- MFMA flash attention, block-cooperative LDS staging ----------------
// Block = 64 consecutive queries (4 waves x 16q) of one (b,h,window).
// Per 128-key chunk: stage K[key][d] (16KB) + V[d][key] (16KB) into LDS once via
// global_load_lds with bank-swizzled source mapping (16B group ^ (row&7)), then
// all 4 waves run S^T = K*Q^T -> per-lane online softmax -> P via LDS -> O^T = V^T*P^T.
__global__ __launch_bounds__(256) void attn_kernel(const u16* __restrict__ qkv,
                                                   const u16* __restrict__ vt,
                                                   u16* __restrict__ o) {
    __shared__ u16 Ks[128 * 64];                   // [key][d], 16B groups swizzled by key&7
    __shared__ u16 Vs[64 * 128];                   // [d][key], 16B groups swizzled by d&7
    __shared__ u16 p_lds[4][16][136];              // per-wave P tile [q][key]
    int tid = threadIdx.x, wave = tid >> 6, lane = tid & 63;
    int quad = lane >> 4, l15 = lane & 15;
    int bi = blockIdx.x;
    int qb = bi & 7, w0 = (bi >> 3) & 7, hh = (bi >> 6) & 15, b = bi >> 10;
    int qt = qb * 4 + wave;                        // q-tile 0..31 within window
    int qlocal = qt * 16 + l15;
    const u16* qp = qkv + (size_t)(b*NSEQ + w0*WIN + qt*16 + l15) * QKV_N + hh*64 + quad*8;
    short8 bq0 = *(const short8*)(qp);
    short8 bq1 = *(const short8*)(qp + 32);
    int krow0 = b * NSEQ + (w0 - 1) * WIN;         // row of combined key 0
    const u16* vbase = vt + (size_t)(b * HEADS + hh) * DH * NSEQ + (w0 - 1) * WIN;
    // staging lane decode
    int ks_row = lane >> 3;                        // key within 8-key group
    int ks_g   = (lane & 7) ^ ks_row;              // swizzled d-group (key&7 == ks_row)
    int vs_row = lane >> 4;                        // d within 4-row group
    int vs_j0  = lane & 15;                        // key-group slot
    int swz = l15 & 7;
    float m_ = -1e30f, l_ = 0.f;
    float4v O[4] = {{0,0,0,0},{0,0,0,0},{0,0,0,0},{0,0,0,0}};
    int cstart = (w0 == 0) ? 4 : 0;
    int clast  = (512 + qb * 64 + 63) >> 7;        // block-shared chunk range
    u16 (*pt)[136] = p_lds[wave];
    for (int c = cstart; c <= clast; c++) {
        int kb = c * 128;
        __syncthreads();                           // prev chunk fully consumed
#pragma unroll
        for (int i = 0; i < 4; i++) {
            int kloc = wave * 32 + i * 8 + ks_row;
            gl_lds16(qkv + (size_t)(krow0 + kb + kloc) * QKV_N + DIM + hh*64 + ks_g*8,
                     &Ks[(wave*32 + i*8) * 64]);
        }
#pragma unroll
        for (int i = 0; i < 4; i++) {
            int dloc = wave * 16 + i * 4 + vs_row;
            int jsrc = vs_j0 ^ (dloc & 7);
            gl_lds16(vbase + (size_t)dloc * NSEQ + kb + jsrc * 8,
                     &Vs[(wave*16 + i*4) * 128]);
        }
        __syncthreads();                           // staging drained (vmcnt(0) at barrier)
        // ---- S^T = K * Q^T ----
        float4v s[8];
#pragma unroll
        for (int t = 0; t < 8; t++) {
            int krow = (t*16 + l15) * 64;
            short8 ka0 = *(const short8*)&Ks[krow + ((quad    ) ^ swz) * 8];
            short8 ka1 = *(const short8*)&Ks[krow + ((quad + 4) ^ swz) * 8];
            float4v st = {0.f, 0.f, 0.f, 0.f};
            st = __builtin_amdgcn_mfma_f32_16x16x32_bf16(ka0, bq0, st, 0, 0, 0);
            st = __builtin_amdgcn_mfma_f32_16x16x32_bf16(ka1, bq1, st, 0, 0, 0);
            int ck = kb + t*16 + quad*4;
#pragma unroll
            for (int r = 0; r < 4; r++)
                if (ck + r >= 512 && ck + r - 512 > qlocal) st[r] = -1e30f;
            s[t] = st;
        }
        // ---- online softmax (per-lane q, reduce across 4 quads) ----
        float mc = -1e30f;
#pragma unroll
        for (int t = 0; t < 8; t++)
#pragma unroll
            for (int r = 0; r < 4; r++) mc = fmaxf(mc, s[t][r]);
        mc = fmaxf(mc, __shfl_xor(mc, 16));
        mc = fmaxf(mc, __shfl_xor(mc, 32));
        float mn = fmaxf(m_, mc);
        float alpha = __expf(m_ - mn);
        m_ = mn;
        float su = 0.f;
#pragma unroll
        for (int t = 0; t < 8; t++) {
            union { u16 h[4]; uint2 v; } pk;
#pragma unroll
            for (int r = 0; r < 4; r++) {
                float p = __expf(s[t][r] - mn);
                su += p;
                pk.h[r] = f2bf(p);
            }
            *(uint2*)&pt[l15][t*16 + quad*4] = pk.v;
        }
        su += __shfl_xor(su, 16);
        su += __shfl_xor(su, 32);
        l_ = l_ * alpha + su;
#pragma unroll
        for (int t = 0; t < 4; t++)
#pragma unroll
            for (int r = 0; r < 4; r++) O[t][r] *= alpha;
        // ---- O^T += V^T * P^T ----
#pragma unroll
        for (int g = 0; g < 4; g++) {
            short8 pf = *(const short8*)&pt[l15][g*32 + quad*8];
#pragma unroll
            for (int t = 0; t < 4; t++) {
                short8 vf = *(const short8*)&Vs[(t*16 + l15) * 128 + ((g*4 + quad) ^ swz) * 8];
                O[t] = __builtin_amdgcn_mfma_f32_16x16x32_bf16(vf, pf, O[t], 0, 0, 0);
            }
        }
    }
    float inv = 1.f / l_;
    u16* op = o + (size_t)(b*NSEQ + w0*WIN + qt*16 + l15) * DIM + hh*64;
#pragma unroll
    for (int t = 0; t < 4; t++) {
        union { u16 h[4]; uint2 v; } pk;
#pragma unroll
        for (int r = 0; r < 4; r++) pk.h[r] = f2bf(O[t][r] * inv);
        *(uint2*)(op + t*16 + quad*4) = pk.v;
    }
}

// ---------------- GEGLU gate (padded strides) ----------------
__global__ __launch_bounds__(256) void geglu_kernel(const u16* __restrict__ u, u16* __restrict__ ag) {
    int col = blockIdx.x * 256 + threadIdx.x;
    int row = blockIdx.y;
    if (col >= INNER_P) return;
    float v = 0.f;
    if (col < INNER) {
        float a = bf2f(u[(size_t)row * FF1_NP + col]);
        float g = bf2f(u[(size_t)row * FF1_NP + INNER + col]);
        v = a * 0.5f * g * (1.f + erff(g * 0.70710678118f));
    }
    ag[(size_t)row * INNER_P + col] = f2bf(v);
}

// ---------------- launch ----------------
extern "C" void kernel_launch(void* const* d_in, const int* in_sizes, int n_in,
                              void* d_out, int out_size, void* d_ws, size_t ws_size,
                              hipStream_t stream) {
    const float* x      = (const float*)d_in[0];
    const float* ln1_w  = (const float*)d_in[1];
    const float* ln1_b  = (const float*)d_in[2];
    const float* w_qkv  = (const float*)d_in[3];
    const float* w_out  = (const float*)d_in[4];
    const float* ln2_w  = (const float*)d_in[5];
    const float* w_ff1  = (const float*)d_in[6];
    const float* w_ff2  = (const float*)d_in[7];
    float* out = (float*)d_out;

    char* ws = (char*)d_ws;
    size_t off = 0;
    auto alloc = [&](size_t bytes) { size_t o = off; off += (bytes + 255) & ~(size_t)255; return o; };
    size_t off_wqt  = alloc((size_t)QKV_N  * DIM * 2);
    size_t off_wot  = alloc((size_t)DIM    * DIM * 2);
    size_t off_wf1t = alloc((size_t)FF1_NP * DIM * 2);
    size_t off_wf2t = alloc((size_t)DIM    * INNER_P * 2);
    size_t off_h    = alloc((size_t)ROWS * DIM * 2);
    size_t sz_qkv = (size_t)ROWS * QKV_N * 2;
    size_t sz_vt  = (size_t)BATCH * HEADS * DH * NSEQ * 2;
    size_t sz_o   = (size_t)ROWS * DIM * 2;
    size_t sz_u   = (size_t)ROWS * FF1_NP * 2;
    size_t r1sz = sz_qkv + sz_vt + sz_o; if (sz_u > r1sz) r1sz = sz_u;
    size_t off_r1   = alloc(r1sz);
    size_t off_x1   = alloc((size_t)ROWS * DIM * 4);
    size_t off_ag   = alloc((size_t)ROWS * INNER_P * 2);

    u16* wqt  = (u16*)(ws + off_wqt);
    u16* wot  = (u16*)(ws + off_wot);
    u16* wf1t = (u16*)(ws + off_wf1t);
    u16* wf2t = (u16*)(ws + off_wf2t);
    u16* h    = (u16*)(ws + off_h);
    u16* qkv  = (u16*)(ws + off_r1);
    u16* vt   = (u16*)(ws + off_r1 + sz_qkv);
    u16* o    = (u16*)(ws + off_r1 + sz_qkv + sz_vt);
    u16* u    = (u16*)(ws + off_r1);
    float* x1 = (float*)(ws + off_x1);
    u16* ag   = (u16*)(ws + off_ag);

    // 0) transpose+cast weights -> bf16 [N][K] (zero-padded)
    wtrans_kernel<<<dim3(32, 96),  256, 0, stream>>>(w_qkv, wqt,  DIM,   QKV_N, DIM,     QKV_N);
    wtrans_kernel<<<dim3(32, 32),  256, 0, stream>>>(w_out, wot,  DIM,   DIM,   DIM,     DIM);
    wtrans_kernel<<<dim3(32, 172), 256, 0, stream>>>(w_ff1, wf1t, DIM,   FF1_N, DIM,     FF1_NP);
    wtrans_kernel<<<dim3(86, 32),  256, 0, stream>>>(w_ff2, wf2t, INNER, DIM,   INNER_P, DIM);

    // 1) LN1
    ln_kernel<<<ROWS, 256, 0, stream>>>(x, ln1_w, ln1_b, h);
    // 2) qkv = h @ w_qkv
    gemm_tile<false><<<(ROWS/128) * (QKV_N/128), 256, 0, stream>>>(h, wqt, nullptr, qkv, ROWS, QKV_N, DIM);
    // 3) rotary + q scale
    rotary_kernel<<<(BATCH * NSEQ * HEADS * 32) / 256, 256, 0, stream>>>(qkv);
    // 4) V transpose
    vtrans_kernel<<<BATCH * HEADS * (NSEQ / 64), 256, 0, stream>>>(qkv, vt);
    // 5) attention
    attn_kernel<<<BATCH * HEADS * 8 * 8, 256, 0, stream>>>(qkv, vt, o);
    // 6) x1 = o @ w_out + x
    gemm_tile<true><<<(ROWS/128) * (DIM/128), 256, 0, stream>>>(o, wot, x, x1, ROWS, DIM, DIM);
    // 7) h2 = LN2(x1)
    ln_kernel<<<ROWS, 256, 0, stream>>>(x1, ln2_w, nullptr, h);
    // 8) u = h2 @ w_ff1 (N padded to 5504)
    gemm_tile<false><<<(ROWS/128) * (FF1_NP/128), 256, 0, stream>>>(h, wf1t, nullptr, u, ROWS, FF1_NP, DIM);
    // 9) ag = a * gelu(g) (K padded to 2752, zero-filled)
    geglu_kernel<<<dim3((INNER_P + 255) / 256, ROWS), 256, 0, stream>>>(u, ag);
    // 10) out = ag @ w_ff2 + x1
    gemm_tile<true><<<(ROWS/128) * (DIM/128), 256, 0, stream>>>(ag, wf2t, x1, out, ROWS, DIM, INNER_P);

    (void)in_sizes; (void)n_in; (void)out_size; (void)ws_size;
}

// Round 6
// 603.285 us; speedup vs baseline: 1.3112x; 1.0735x over previous
//
#include <hip/hip_runtime.h>
#include <stdint.h>

typedef unsigned short u16;
typedef unsigned int u32;

// ---------------- constants ----------------
#define BATCH 2
#define NSEQ  4096
#define DIM   1024
#define HEADS 16
#define DH    64
#define WIN   512
#define INNER 2730
#define ROWS  8192
#define QKV_N 3072
#define FF1_N 5460
#define FF1_NP 5504      // padded N for ff1 (43*128)
#define INNER_P 2752     // padded K for ff2 (86*32)
#define KROT 0.28782313663f   // ln(10000)/32

typedef __attribute__((ext_vector_type(8))) short short8;
typedef __attribute__((ext_vector_type(4))) float float4v;

__device__ __forceinline__ float bf2f(u16 u){ union{u32 i;float f;}c; c.i=((u32)u)<<16; return c.f; }
__device__ __forceinline__ u16 f2bf(float f){ union{float f;u32 i;}c; c.f=f; u32 i=c.i;
    return (u16)((i + 0x7FFFu + ((i>>16)&1u))>>16); }

// async global->LDS, 16B per lane. LDS dest = wave-uniform base + lane*16; global src may scatter per lane.
__device__ __forceinline__ void gl_lds16(const u16* g, const u16* ldsbase) {
    __builtin_amdgcn_global_load_lds(
        (const __attribute__((address_space(1))) u32*)(uintptr_t)g,
        (__attribute__((address_space(3))) u32*)(uintptr_t)ldsbase,
        16, 0, 0);
}

// ff1 interleave mapping: output row n' of wf1t -> source column of w_ff1
__device__ __forceinline__ int ff1_src(int n, bool& ok) {
    int t = n >> 7, m = n & 127, j = m >> 4, l = m & 15;
    int p = t * 64 + ((j >> 1) << 4) + l;
    ok = (p < INNER);
    return (j & 1) ? (INNER + p) : p;
}

// ---------------- weight transpose + cast: wt[n][k] = bf16(w[k][src(n)]), zero-padded ----------------
template <bool REMAP>
__global__ __launch_bounds__(256) void wtrans_kernel(const float* __restrict__ w, u16* __restrict__ wt,
                                                     int K0, int N0, int K1, int N1) {
    __shared__ float tile[32][33];
    int kt = blockIdx.x, nt = blockIdx.y;
    int tx = threadIdx.x & 31, ty = threadIdx.x >> 5;
    int nl = nt * 32 + tx;
    bool ok = (nl < N1);
    int sc = nl;
    if (REMAP) { bool v; sc = ff1_src(nl < N1 ? nl : 0, v); ok = ok && v; }
    else ok = ok && (nl < N0);
#pragma unroll
    for (int yy = 0; yy < 4; yy++) {
        int k = kt*32 + ty + yy*8;
        tile[ty+yy*8][tx] = (k < K0 && ok) ? w[(size_t)k*N0 + sc] : 0.f;
    }
    __syncthreads();
#pragma unroll
    for (int yy = 0; yy < 4; yy++) {
        int n = nt*32 + ty + yy*8, k = kt*32 + tx;
        if (n < N1 && k < K1) wt[(size_t)n*K1 + k] = f2bf(tile[tx][ty+yy*8]);
    }
}

// ---------------- LayerNorm: fp32 in, bf16 out (dim = 1024) ----------------
__global__ __launch_bounds__(256) void ln_kernel(const float* __restrict__ x,
                                                 const float* __restrict__ w,
                                                 const float* __restrict__ b,
                                                 u16* __restrict__ out) {
    int row = blockIdx.x;
    const float* xr = x + (size_t)row * DIM;
    int t = threadIdx.x;
    float v[4];
    float s = 0.f, s2 = 0.f;
#pragma unroll
    for (int i = 0; i < 4; i++) {
        float f = xr[t + 256 * i];
        v[i] = f; s += f; s2 += f * f;
    }
#pragma unroll
    for (int off = 32; off; off >>= 1) { s += __shfl_xor(s, off); s2 += __shfl_xor(s2, off); }
    __shared__ float ls[10];
    int wave = t >> 6, lane = t & 63;
    if (lane == 0) { ls[wave] = s; ls[4 + wave] = s2; }
    __syncthreads();
    if (t == 0) {
        float ts  = ls[0] + ls[1] + ls[2] + ls[3];
        float ts2 = ls[4] + ls[5] + ls[6] + ls[7];
        float mean = ts * (1.f / DIM);
        float var  = ts2 * (1.f / DIM) - mean * mean;
        ls[8] = mean; ls[9] = 1.f / sqrtf(var + 1e-5f);
    }
    __syncthreads();
    float mean = ls[8], inv = ls[9];
    u16* orow = out + (size_t)row * DIM;
#pragma unroll
    for (int i = 0; i < 4; i++) {
        int c = t + 256 * i;
        float y = (v[i] - mean) * inv * w[c];
        if (b) y += b[c];
        orow[c] = f2bf(y);
    }
}

// ---------------- GEMM: C[M,N] = A[M,K] @ Bt[N,K]^T, fused epilogues ----------------
// MODE 0: bf16 out. MODE 1: fp32 out + fp32 resid. MODE 2: bf16 out + rotary/scale (qkv).
// MODE 3: bf16 GEGLU out, width INNER_P (ff1, interleaved wf1t).
// LDS XOR-swizzled (16B group ^ ((row>>1)&3)) to kill ds_read_b128 bank conflicts.
template <int MODE>
__global__ __launch_bounds__(256) void gemm_tile(const u16* __restrict__ A,
                                                 const u16* __restrict__ Bt,
                                                 const float* __restrict__ resid,
                                                 void* __restrict__ Cv,
                                                 int M, int N, int K) {
    __shared__ u16 As[128 * 32];
    __shared__ u16 Bs[128 * 32];
    int tiles_n = N >> 7;
    int tm = blockIdx.x / tiles_n, tn = blockIdx.x % tiles_n;
    int tid = threadIdx.x, wave = tid >> 6, lane = tid & 63;
    int quad = lane >> 4, l15 = lane & 15;
    int wm = wave >> 1, wn = wave & 1;
    int srow = wave * 32 + (lane >> 2);
    int sgrp = (lane & 3) ^ ((srow >> 1) & 3);      // swizzled source 16B group
    const u16* Ag = A  + (size_t)(tm * 128 + srow) * K + sgrp * 8;
    const u16* Bg = Bt + (size_t)(tn * 128 + srow) * K + sgrp * 8;
    const u16* Alb = &As[wave * 1024];
    const u16* Blb = &Bs[wave * 1024];
    int rg = (l15 >> 1) & 3;                        // reader swizzle term
    float4v acc[4][4];
#pragma unroll
    for (int i = 0; i < 4; i++)
#pragma unroll
        for (int j = 0; j < 4; j++) acc[i][j] = (float4v){0.f, 0.f, 0.f, 0.f};
    for (int k0 = 0; k0 < K; k0 += 32) {
        __syncthreads();
        gl_lds16(Ag + k0,                 Alb);
        gl_lds16(Ag + (size_t)16*K + k0,  Alb + 512);
        gl_lds16(Bg + k0,                 Blb);
        gl_lds16(Bg + (size_t)16*K + k0,  Blb + 512);
        __syncthreads();
        short8 af[4], bf[4];
#pragma unroll
        for (int i = 0; i < 4; i++)
            af[i] = *(const short8*)&As[(wm*64 + i*16 + l15)*32 + ((0 ^ rg))*0 + ( ( ( i*0 ) ) ) + ((quad ^ rg) * 8)];
#pragma unroll
        for (int j = 0; j < 4; j++)
            bf[j] = *(const short8*)&Bs[(wn*64 + j*16 + l15)*32 + ((quad ^ rg) * 8)];
#pragma unroll
        for (int i = 0; i < 4; i++)
#pragma unroll
            for (int j = 0; j < 4; j++)
                acc[i][j] = __builtin_amdgcn_mfma_f32_16x16x32_bf16(af[i], bf[j], acc[i][j], 0, 0, 0);
    }
    // ---------------- epilogues ----------------
    if (MODE == 3) {
        u16* ag = (u16*)Cv;
#pragma unroll
        for (int i = 0; i < 4; i++) {
#pragma unroll
            for (int r = 0; r < 4; r++) {
                size_t row = (size_t)(tm*128 + wm*64 + i*16 + quad*4 + r);
#pragma unroll
                for (int jp = 0; jp < 2; jp++) {
                    float a = acc[i][2*jp][r];
                    float g = acc[i][2*jp+1][r];
                    float ge = 0.5f * g * (1.f + erff(g * 0.70710678118f));
                    int col = tn*64 + wn*32 + jp*16 + l15;
                    ag[row * INNER_P + col] = f2bf(a * ge);
                }
            }
        }
        return;
    }
    if (MODE == 2) {
        u16* C = (u16*)Cv;
        int sector = tn >> 3;                       // 0=q,1=k,2=v
        if (sector < 2) {
            float inv0 = __expf(-(float)l15 * KROT);
            float inv1 = __expf(-(float)(l15 + 16) * KROT);
            float sc = (sector == 0) ? 0.125f : 1.0f;
#pragma unroll
            for (int i = 0; i < 4; i++) {
#pragma unroll
                for (int r = 0; r < 4; r++) {
                    int row = tm*128 + wm*64 + i*16 + quad*4 + r;
                    float fn = (float)(row & (NSEQ - 1));
                    float s0, c0, s1, c1;
                    __sincosf(fn * inv0, &s0, &c0);
                    __sincosf(fn * inv1, &s1, &c1);
                    float a0 = acc[i][0][r], a1 = acc[i][1][r];
                    float a2 = acc[i][2][r], a3 = acc[i][3][r];
                    size_t base = (size_t)row * N + tn*128 + wn*64 + l15;
                    C[base]      = f2bf((a0*c0 - a2*s0) * sc);
                    C[base + 16] = f2bf((a1*c1 - a3*s1) * sc);
                    C[base + 32] = f2bf((a2*c0 + a0*s0) * sc);
                    C[base + 48] = f2bf((a3*c1 + a1*s1) * sc);
                }
            }
        } else {
#pragma unroll
            for (int i = 0; i < 4; i++)
#pragma unroll
                for (int r = 0; r < 4; r++) {
                    size_t base = (size_t)(tm*128 + wm*64 + i*16 + quad*4 + r) * N + tn*128 + wn*64 + l15;
#pragma unroll
                    for (int j = 0; j < 4; j++) C[base + j*16] = f2bf(acc[i][j][r]);
                }
        }
        return;
    }
#pragma unroll
    for (int i = 0; i < 4; i++) {
#pragma unroll
        for (int r = 0; r < 4; r++) {
            size_t row = (size_t)(tm*128 + wm*64 + i*16 + quad*4 + r);
#pragma unroll
            for (int j = 0; j < 4; j++) {
                int col = tn*128 + wn*64 + j*16 + l15;
                size_t idx = row * N + col;
                float v = acc[i][j][r];
                if (MODE == 1) { if (resid) v += resid[idx]; ((float*)Cv)[idx] = v; }
                else ((u16*)Cv)[idx] = f2bf(v);
            }
        }
    }
}

// ---------------- V transpose: vt[b][h][d][n] = qkv.v[b,n,h,d] ----------------
__global__ __launch_bounds__(256) void vtrans_kernel(const u16* __restrict__ qkv, u16* __restrict__ vt) {
    __shared__ u16 tile[64][72];
    int t = threadIdx.x;
    int n0 = (blockIdx.x & 63) * 64;
    int hh = (blockIdx.x >> 6) & 15;
    int b  = blockIdx.x >> 10;
    int r = t >> 2, cb = (t & 3) * 16;
    const u16* src = qkv + (size_t)(b * NSEQ + n0 + r) * QKV_N + 2 * DIM + hh * 64 + cb;
    uint4 v0 = *(const uint4*)(src);
    uint4 v1 = *(const uint4*)(src + 8);
    *(uint4*)&tile[r][cb]     = v0;
    *(uint4*)&tile[r][cb + 8] = v1;
    __syncthreads();
    int d = t >> 2, nb = (t & 3) * 16;
    __align__(16) u16 vals[16];
#pragma unroll
    for (int e = 0; e < 16; e++) vals[e] = tile[nb + e][d];
    u16* dst = vt + ((size_t)(b * HEADS + hh) * DH + d) * NSEQ + n0 + nb;
    *(uint4*)(dst)     = *(uint4*)&vals[0];
    *(uint4*)(dst + 8) = *(uint4*)&vals[8];
}

// ---------------- MFMA flash attention, block-cooperative LDS staging ----------------
__global__ __launch_bounds__(256) void attn_kernel(const u16* __restrict__ qkv,
                                                   const u16* __restrict__ vt,
                                                   u16* __restrict__ o) {
    __shared__ u16 Ks[128 * 64];                   // [key][d], 16B groups swizzled by key&7
    __shared__ u16 Vs[64 * 128];                   // [d][key], 16B groups swizzled by d&7
    __shared__ u16 p_lds[4][16][136];              // per-wave P tile [q][key]
    int tid = threadIdx.x, wave = tid >> 6, lane = tid & 63;
    int quad = lane >> 4, l15 = lane & 15;
    int bi = blockIdx.x;
    int qb = bi & 7, w0 = (bi >> 3) & 7, hh = (bi >> 6) & 15, b = bi >> 10;
    int qt = qb * 4 + wave;
    int qlocal = qt * 16 + l15;
    const u16* qp = qkv + (size_t)(b*NSEQ + w0*WIN + qt*16 + l15) * QKV_N + hh*64 + quad*8;
    short8 bq0 = *(const short8*)(qp);
    short8 bq1 = *(const short8*)(qp + 32);
    int krow0 = b * NSEQ + (w0 - 1) * WIN;
    const u16* vbase = vt + (size_t)(b * HEADS + hh) * DH * NSEQ + (w0 - 1) * WIN;
    int ks_row = lane >> 3;
    int ks_g   = (lane & 7) ^ ks_row;
    int vs_row = lane >> 4;
    int vs_j0  = lane & 15;
    int swz = l15 & 7;
    float m_ = -1e30f, l_ = 0.f;
    float4v O[4] = {{0,0,0,0},{0,0,0,0},{0,0,0,0},{0,0,0,0}};
    int cstart = (w0 == 0) ? 4 : 0;
    int clast  = (512 + qb * 64 + 63) >> 7;
    u16 (*pt)[136] = p_lds[wave];
    for (int c = cstart; c <= clast; c++) {
        int kb = c * 128;
        __syncthreads();
#pragma unroll
        for (int i = 0; i < 4; i++) {
            int kloc = wave * 32 + i * 8 + ks_row;
            gl_lds16(qkv + (size_t)(krow0 + kb + kloc) * QKV_N + DIM + hh*64 + ks_g*8,
                     &Ks[(wave*32 + i*8) * 64]);
        }
#pragma unroll
        for (int i = 0; i < 4; i++) {
            int dloc = wave * 16 + i * 4 + vs_row;
            int jsrc = vs_j0 ^ (dloc & 7);
            gl_lds16(vbase + (size_t)dloc * NSEQ + kb + jsrc * 8,
                     &Vs[(wave*16 + i*4) * 128]);
        }
        __syncthreads();
        float4v s[8];
#pragma unroll
        for (int t = 0; t < 8; t++) {
            int krow = (t*16 + l15) * 64;
            short8 ka0 = *(const short8*)&Ks[krow + ((quad    ) ^ swz) * 8];
            short8 ka1 = *(const short8*)&Ks[krow + ((quad + 4) ^ swz) * 8];
            float4v st = {0.f, 0.f, 0.f, 0.f};
            st = __builtin_amdgcn_mfma_f32_16x16x32_bf16(ka0, bq0, st, 0, 0, 0);
            st = __builtin_amdgcn_mfma_f32_16x16x32_bf16(ka1, bq1, st, 0, 0, 0);
            int ck = kb + t*16 + quad*4;
#pragma unroll
            for (int r = 0; r < 4; r++)
                if (ck + r >= 512 && ck + r - 512 > qlocal) st[r] = -1e30f;
            s[t] = st;
        }
        float mc = -1e30f;
#pragma unroll
        for (int t = 0; t < 8; t++)
#pragma unroll
            for (int r = 0; r < 4; r++) mc = fmaxf(mc, s[t][r]);
        mc = fmaxf(mc, __shfl_xor(mc, 16));
        mc = fmaxf(mc, __shfl_xor(mc, 32));
        float mn = fmaxf(m_, mc);
        float alpha = __expf(m_ - mn);
        m_ = mn;
        float su = 0.f;
#pragma unroll
        for (int t = 0; t < 8; t++) {
            union { u16 h[4]; uint2 v; } pk;
#pragma unroll
            for (int r = 0; r < 4; r++) {
                float p = __expf(s[t][r] - mn);
                su += p;
                pk.h[r] = f2bf(p);
            }
            *(uint2*)&pt[l15][t*16 + quad*4] = pk.v;
        }
        su += __shfl_xor(su, 16);
        su += __shfl_xor(su, 32);
        l_ = l_ * alpha + su;
#pragma unroll
        for (int t = 0; t < 4; t++)
#pragma unroll
            for (int r = 0; r < 4; r++) O[t][r] *= alpha;
#pragma unroll
        for (int g = 0; g < 4; g++) {
            short8 pf = *(const short8*)&pt[l15][g*32 + quad*8];
#pragma unroll
            for (int t = 0; t < 4; t++) {
                short8 vf = *(const short8*)&Vs[(t*16 + l15) * 128 + ((g*4 + quad) ^ swz) * 8];
                O[t] = __builtin_amdgcn_mfma_f32_16x16x32_bf16(vf, pf, O[t], 0, 0, 0);
            }
        }
    }
    float inv = 1.f / l_;
    u16* op = o + (size_t)(b*NSEQ + w0*WIN + qt*16 + l15) * DIM + hh*64;
#pragma unroll
    for (int t = 0; t < 4; t++) {
        union { u16 h[4]; uint2 v; } pk;
#pragma unroll
        for (int r = 0; r < 4; r++) pk.h[r] = f2bf(O[t][r] * inv);
        *(uint2*)(op + t*16 + quad*4) = pk.v;
    }
}

// ---------------- launch ----------------
extern "C" void kernel_launch(void* const* d_in, const int* in_sizes, int n_in,
                              void* d_out, int out_size, void* d_ws, size_t ws_size,
                              hipStream_t stream) {
    const float* x      = (const float*)d_in[0];
    const float* ln1_w  = (const float*)d_in[1];
    const float* ln1_b  = (const float*)d_in[2];
    const float* w_qkv  = (const float*)d_in[3];
    const float* w_out  = (const float*)d_in[4];
    const float* ln2_w  = (const float*)d_in[5];
    const float* w_ff1  = (const float*)d_in[6];
    const float* w_ff2  = (const float*)d_in[7];
    float* out = (float*)d_out;

    char* ws = (char*)d_ws;
    size_t off = 0;
    auto alloc = [&](size_t bytes) { size_t o = off; off += (bytes + 255) & ~(size_t)255; return o; };
    size_t off_wqt  = alloc((size_t)QKV_N  * DIM * 2);
    size_t off_wot  = alloc((size_t)DIM    * DIM * 2);
    size_t off_wf1t = alloc((size_t)FF1_NP * DIM * 2);
    size_t off_wf2t = alloc((size_t)DIM    * INNER_P * 2);
    size_t off_h    = alloc((size_t)ROWS * DIM * 2);
    size_t sz_qkv = (size_t)ROWS * QKV_N * 2;
    size_t sz_vt  = (size_t)BATCH * HEADS * DH * NSEQ * 2;
    size_t off_qkv  = alloc(sz_qkv);
    size_t off_vt   = alloc(sz_vt);
    size_t off_o    = alloc((size_t)ROWS * DIM * 2);
    size_t off_x1   = alloc((size_t)ROWS * DIM * 4);
    size_t off_ag   = alloc((size_t)ROWS * INNER_P * 2);

    u16* wqt  = (u16*)(ws + off_wqt);
    u16* wot  = (u16*)(ws + off_wot);
    u16* wf1t = (u16*)(ws + off_wf1t);
    u16* wf2t = (u16*)(ws + off_wf2t);
    u16* h    = (u16*)(ws + off_h);
    u16* qkv  = (u16*)(ws + off_qkv);
    u16* vt   = (u16*)(ws + off_vt);
    u16* o    = (u16*)(ws + off_o);
    float* x1 = (float*)(ws + off_x1);
    u16* ag   = (u16*)(ws + off_ag);

    // 0) transpose+cast weights -> bf16 [N][K]; ff1 column-interleaved (a,g) pairs
    wtrans_kernel<false><<<dim3(32, 96),  256, 0, stream>>>(w_qkv, wqt,  DIM,   QKV_N, DIM,     QKV_N);
    wtrans_kernel<false><<<dim3(32, 32),  256, 0, stream>>>(w_out, wot,  DIM,   DIM,   DIM,     DIM);
    wtrans_kernel<true ><<<dim3(32, 172), 256, 0, stream>>>(w_ff1, wf1t, DIM,   FF1_N, DIM,     FF1_NP);
    wtrans_kernel<false><<<dim3(86, 32),  256, 0, stream>>>(w_ff2, wf2t, INNER, DIM,   INNER_P, DIM);

    // 1) LN1
    ln_kernel<<<ROWS, 256, 0, stream>>>(x, ln1_w, ln1_b, h);
    // 2) qkv = h @ w_qkv, rotary+scale fused in epilogue
    gemm_tile<2><<<(ROWS/128) * (QKV_N/128), 256, 0, stream>>>(h, wqt, nullptr, qkv, ROWS, QKV_N, DIM);
    // 3) V transpose
    vtrans_kernel<<<BATCH * HEADS * (NSEQ / 64), 256, 0, stream>>>(qkv, vt);
    // 4) attention
    attn_kernel<<<BATCH * HEADS * 8 * 8, 256, 0, stream>>>(qkv, vt, o);
    // 5) x1 = o @ w_out + x
    gemm_tile<1><<<(ROWS/128) * (DIM/128), 256, 0, stream>>>(o, wot, x, x1, ROWS, DIM, DIM);
    // 6) h2 = LN2(x1)
    ln_kernel<<<ROWS, 256, 0, stream>>>(x1, ln2_w, nullptr, h);
    // 7) ag = geglu(h2 @ w_ff1) fused (interleaved wf1t), writes [8192 x 2752]
    gemm_tile<3><<<(ROWS/128) * (FF1_NP/128), 256, 0, stream>>>(h, wf1t, nullptr, ag, ROWS, FF1_NP, DIM);
    // 8) out = ag @ w_ff2 + x1
    gemm_tile<1><<<(ROWS/128) * (DIM/128), 256, 0, stream>>>(ag, wf2t, x1, out, ROWS, DIM, INNER_P);

    (void)in_sizes; (void)n_in; (void)out_size; (void)ws_size;
}

// Round 7
// 577.673 us; speedup vs baseline: 1.3693x; 1.0443x over previous
//
#include <hip/hip_runtime.h>
#include <stdint.h>

typedef unsigned short u16;
typedef unsigned int u32;

// ---------------- constants ----------------
#define BATCH 2
#define NSEQ  4096
#define DIM   1024
#define HEADS 16
#define DH    64
#define WIN   512
#define INNER 2730
#define ROWS  8192
#define QKV_N 3072
#define FF1_N 5460
#define FF1_NP 5504      // padded N for ff1 (43*128)
#define INNER_P 2752     // padded K for ff2 (86*32)
#define KROT 0.28782313663f   // ln(10000)/32

typedef __attribute__((ext_vector_type(8))) short short8;
typedef __attribute__((ext_vector_type(4))) float float4v;

__device__ __forceinline__ float bf2f(u16 u){ union{u32 i;float f;}c; c.i=((u32)u)<<16; return c.f; }
__device__ __forceinline__ u16 f2bf(float f){ union{float f;u32 i;}c; c.f=f; u32 i=c.i;
    return (u16)((i + 0x7FFFu + ((i>>16)&1u))>>16); }

// fast GELU (tanh form via hw exp): |err vs exact| <= ~3e-3, fine at 0.109 threshold
__device__ __forceinline__ float gelu_fast(float g) {
    float t = 0.7978845608f * (g + 0.044715f * g * g * g);
    // tanh(t) = 1 - 2/(1+e^{2t})
    float th = 1.f - 2.f / (1.f + __expf(2.f * t));
    return 0.5f * g * (1.f + th);
}

// async global->LDS, 16B per lane. LDS dest = wave-uniform base + lane*16; global src may scatter per lane.
__device__ __forceinline__ void gl_lds16(const u16* g, const u16* ldsbase) {
    __builtin_amdgcn_global_load_lds(
        (const __attribute__((address_space(1))) u32*)(uintptr_t)g,
        (__attribute__((address_space(3))) u32*)(uintptr_t)ldsbase,
        16, 0, 0);
}

// ff1 interleave mapping: output row n' of wf1t -> source column of w_ff1
__device__ __forceinline__ int ff1_src(int n, bool& ok) {
    int t = n >> 7, m = n & 127, j = m >> 4, l = m & 15;
    int p = t * 64 + ((j >> 1) << 4) + l;
    ok = (p < INNER);
    return (j & 1) ? (INNER + p) : p;
}

// ---------------- weight transpose + cast: wt[n][k] = bf16(w[k][src(n)]), zero-padded ----------------
template <bool REMAP>
__global__ __launch_bounds__(256) void wtrans_kernel(const float* __restrict__ w, u16* __restrict__ wt,
                                                     int K0, int N0, int K1, int N1) {
    __shared__ float tile[32][33];
    int kt = blockIdx.x, nt = blockIdx.y;
    int tx = threadIdx.x & 31, ty = threadIdx.x >> 5;
    int nl = nt * 32 + tx;
    bool ok = (nl < N1);
    int sc = nl;
    if (REMAP) { bool v; sc = ff1_src(nl < N1 ? nl : 0, v); ok = ok && v; }
    else ok = ok && (nl < N0);
#pragma unroll
    for (int yy = 0; yy < 4; yy++) {
        int k = kt*32 + ty + yy*8;
        tile[ty+yy*8][tx] = (k < K0 && ok) ? w[(size_t)k*N0 + sc] : 0.f;
    }
    __syncthreads();
#pragma unroll
    for (int yy = 0; yy < 4; yy++) {
        int n = nt*32 + ty + yy*8, k = kt*32 + tx;
        if (n < N1 && k < K1) wt[(size_t)n*K1 + k] = f2bf(tile[tx][ty+yy*8]);
    }
}

// ---------------- LayerNorm: fp32 in, bf16 out (dim = 1024) ----------------
__global__ __launch_bounds__(256) void ln_kernel(const float* __restrict__ x,
                                                 const float* __restrict__ w,
                                                 const float* __restrict__ b,
                                                 u16* __restrict__ out) {
    int row = blockIdx.x;
    const float* xr = x + (size_t)row * DIM;
    int t = threadIdx.x;
    float v[4];
    float s = 0.f, s2 = 0.f;
#pragma unroll
    for (int i = 0; i < 4; i++) {
        float f = xr[t + 256 * i];
        v[i] = f; s += f; s2 += f * f;
    }
#pragma unroll
    for (int off = 32; off; off >>= 1) { s += __shfl_xor(s, off); s2 += __shfl_xor(s2, off); }
    __shared__ float ls[10];
    int wave = t >> 6, lane = t & 63;
    if (lane == 0) { ls[wave] = s; ls[4 + wave] = s2; }
    __syncthreads();
    if (t == 0) {
        float ts  = ls[0] + ls[1] + ls[2] + ls[3];
        float ts2 = ls[4] + ls[5] + ls[6] + ls[7];
        float mean = ts * (1.f / DIM);
        float var  = ts2 * (1.f / DIM) - mean * mean;
        ls[8] = mean; ls[9] = 1.f / sqrtf(var + 1e-5f);
    }
    __syncthreads();
    float mean = ls[8], inv = ls[9];
    u16* orow = out + (size_t)row * DIM;
#pragma unroll
    for (int i = 0; i < 4; i++) {
        int c = t + 256 * i;
        float y = (v[i] - mean) * inv * w[c];
        if (b) y += b[c];
        orow[c] = f2bf(y);
    }
}

// ---------------- GEMM: C[M,N] = A[M,K] @ Bt[N,K]^T, fused epilogues ----------------
// MODE 0: bf16 out. MODE 1: fp32 out + fp32 resid. MODE 2: bf16 out + rotary/scale (qkv).
// MODE 3: bf16 GEGLU out, width INNER_P (ff1, interleaved wf1t).
// LDS XOR-swizzled (16B group ^ ((row>>1)&3)); grouped tile order (GROUP_M=8) for L2 locality.
template <int MODE>
__global__ __launch_bounds__(256) void gemm_tile(const u16* __restrict__ A,
                                                 const u16* __restrict__ Bt,
                                                 const float* __restrict__ resid,
                                                 void* __restrict__ Cv,
                                                 int M, int N, int K) {
    __shared__ u16 As[128 * 32];
    __shared__ u16 Bs[128 * 32];
    int tiles_n = N >> 7;
    // grouped ordering: 8 m-tiles per supergroup, tm fast within each 8-block run
    int gs  = tiles_n << 3;
    int gid = blockIdx.x / gs;
    int loc = blockIdx.x % gs;
    int tm = gid * 8 + (loc & 7);
    int tn = loc >> 3;
    int tid = threadIdx.x, wave = tid >> 6, lane = tid & 63;
    int quad = lane >> 4, l15 = lane & 15;
    int wm = wave >> 1, wn = wave & 1;
    int srow = wave * 32 + (lane >> 2);
    int sgrp = (lane & 3) ^ ((srow >> 1) & 3);      // swizzled source 16B group
    const u16* Ag = A  + (size_t)(tm * 128 + srow) * K + sgrp * 8;
    const u16* Bg = Bt + (size_t)(tn * 128 + srow) * K + sgrp * 8;
    const u16* Alb = &As[wave * 1024];
    const u16* Blb = &Bs[wave * 1024];
    int rg = (l15 >> 1) & 3;                        // reader swizzle term
    float4v acc[4][4];
#pragma unroll
    for (int i = 0; i < 4; i++)
#pragma unroll
        for (int j = 0; j < 4; j++) acc[i][j] = (float4v){0.f, 0.f, 0.f, 0.f};
    for (int k0 = 0; k0 < K; k0 += 32) {
        __syncthreads();
        gl_lds16(Ag + k0,                 Alb);
        gl_lds16(Ag + (size_t)16*K + k0,  Alb + 512);
        gl_lds16(Bg + k0,                 Blb);
        gl_lds16(Bg + (size_t)16*K + k0,  Blb + 512);
        __syncthreads();
        short8 af[4], bf[4];
#pragma unroll
        for (int i = 0; i < 4; i++)
            af[i] = *(const short8*)&As[(wm*64 + i*16 + l15)*32 + ((quad ^ rg) * 8)];
#pragma unroll
        for (int j = 0; j < 4; j++)
            bf[j] = *(const short8*)&Bs[(wn*64 + j*16 + l15)*32 + ((quad ^ rg) * 8)];
#pragma unroll
        for (int i = 0; i < 4; i++)
#pragma unroll
            for (int j = 0; j < 4; j++)
                acc[i][j] = __builtin_amdgcn_mfma_f32_16x16x32_bf16(af[i], bf[j], acc[i][j], 0, 0, 0);
    }
    // ---------------- epilogues ----------------
    if (MODE == 3) {
        u16* ag = (u16*)Cv;
#pragma unroll
        for (int i = 0; i < 4; i++) {
#pragma unroll
            for (int r = 0; r < 4; r++) {
                size_t row = (size_t)(tm*128 + wm*64 + i*16 + quad*4 + r);
#pragma unroll
                for (int jp = 0; jp < 2; jp++) {
                    float a = acc[i][2*jp][r];
                    float g = acc[i][2*jp+1][r];
                    int col = tn*64 + wn*32 + jp*16 + l15;
                    ag[row * INNER_P + col] = f2bf(a * gelu_fast(g));
                }
            }
        }
        return;
    }
    if (MODE == 2) {
        u16* C = (u16*)Cv;
        int sector = tn >> 3;                       // 0=q,1=k,2=v
        if (sector < 2) {
            float inv0 = __expf(-(float)l15 * KROT);
            float inv1 = __expf(-(float)(l15 + 16) * KROT);
            float sc = (sector == 0) ? 0.125f : 1.0f;
#pragma unroll
            for (int i = 0; i < 4; i++) {
#pragma unroll
                for (int r = 0; r < 4; r++) {
                    int row = tm*128 + wm*64 + i*16 + quad*4 + r;
                    float fn = (float)(row & (NSEQ - 1));
                    float s0, c0, s1, c1;
                    __sincosf(fn * inv0, &s0, &c0);
                    __sincosf(fn * inv1, &s1, &c1);
                    float a0 = acc[i][0][r], a1 = acc[i][1][r];
                    float a2 = acc[i][2][r], a3 = acc[i][3][r];
                    size_t base = (size_t)row * N + tn*128 + wn*64 + l15;
                    C[base]      = f2bf((a0*c0 - a2*s0) * sc);
                    C[base + 16] = f2bf((a1*c1 - a3*s1) * sc);
                    C[base + 32] = f2bf((a2*c0 + a0*s0) * sc);
                    C[base + 48] = f2bf((a3*c1 + a1*s1) * sc);
                }
            }
        } else {
#pragma unroll
            for (int i = 0; i < 4; i++)
#pragma unroll
                for (int r = 0; r < 4; r++) {
                    size_t base = (size_t)(tm*128 + wm*64 + i*16 + quad*4 + r) * N + tn*128 + wn*64 + l15;
#pragma unroll
                    for (int j = 0; j < 4; j++) C[base + j*16] = f2bf(acc[i][j][r]);
                }
        }
        return;
    }
#pragma unroll
    for (int i = 0; i < 4; i++) {
#pragma unroll
        for (int r = 0; r < 4; r++) {
            size_t row = (size_t)(tm*128 + wm*64 + i*16 + quad*4 + r);
#pragma unroll
            for (int j = 0; j < 4; j++) {
                int col = tn*128 + wn*64 + j*16 + l15;
                size_t idx = row * N + col;
                float v = acc[i][j][r];
                if (MODE == 1) { if (resid) v += resid[idx]; ((float*)Cv)[idx] = v; }
                else ((u16*)Cv)[idx] = f2bf(v);
            }
        }
    }
}

// ---------------- V transpose: vt[b][h][d][n] = qkv.v[b,n,h,d] ----------------
__global__ __launch_bounds__(256) void vtrans_kernel(const u16* __restrict__ qkv, u16* __restrict__ vt) {
    __shared__ u16 tile[64][72];
    int t = threadIdx.x;
    int n0 = (blockIdx.x & 63) * 64;
    int hh = (blockIdx.x >> 6) & 15;
    int b  = blockIdx.x >> 10;
    int r = t >> 2, cb = (t & 3) * 16;
    const u16* src = qkv + (size_t)(b * NSEQ + n0 + r) * QKV_N + 2 * DIM + hh * 64 + cb;
    uint4 v0 = *(const uint4*)(src);
    uint4 v1 = *(const uint4*)(src + 8);
    *(uint4*)&tile[r][cb]     = v0;
    *(uint4*)&tile[r][cb + 8] = v1;
    __syncthreads();
    int d = t >> 2, nb = (t & 3) * 16;
    __align__(16) u16 vals[16];
#pragma unroll
    for (int e = 0; e < 16; e++) vals[e] = tile[nb + e][d];
    u16* dst = vt + ((size_t)(b * HEADS + hh) * DH + d) * NSEQ + n0 + nb;
    *(uint4*)(dst)     = *(uint4*)&vals[0];
    *(uint4*)(dst + 8) = *(uint4*)&vals[8];
}

// ---------------- MFMA flash attention, block-cooperative LDS staging ----------------
__global__ __launch_bounds__(256) void attn_kernel(const u16* __restrict__ qkv,
                                                   const u16* __restrict__ vt,
                                                   u16* __restrict__ o) {
    __shared__ u16 Ks[128 * 64];                   // [key][d], 16B groups swizzled by key&7
    __shared__ u16 Vs[64 * 128];                   // [d][key], 16B groups swizzled by d&7
    __shared__ u16 p_lds[4][16][136];              // per-wave P tile [q][key]
    int tid = threadIdx.x, wave = tid >> 6, lane = tid & 63;
    int quad = lane >> 4, l15 = lane & 15;
    int bi = blockIdx.x;
    int qb = bi & 7, w0 = (bi >> 3) & 7, hh = (bi >> 6) & 15, b = bi >> 10;
    int qt = qb * 4 + wave;
    int qlocal = qt * 16 + l15;
    const u16* qp = qkv + (size_t)(b*NSEQ + w0*WIN + qt*16 + l15) * QKV_N + hh*64 + quad*8;
    short8 bq0 = *(const short8*)(qp);
    short8 bq1 = *(const short8*)(qp + 32);
    int krow0 = b * NSEQ + (w0 - 1) * WIN;
    const u16* vbase = vt + (size_t)(b * HEADS + hh) * DH * NSEQ + (w0 - 1) * WIN;
    int ks_row = lane >> 3;
    int ks_g   = (lane & 7) ^ ks_row;
    int vs_row = lane >> 4;
    int vs_j0  = lane & 15;
    int swz = l15 & 7;
    float m_ = -1e30f, l_ = 0.f;
    float4v O[4] = {{0,0,0,0},{0,0,0,0},{0,0,0,0},{0,0,0,0}};
    int cstart = (w0 == 0) ? 4 : 0;
    int clast  = (512 + qb * 64 + 63) >> 7;
    u16 (*pt)[136] = p_lds[wave];
    for (int c = cstart; c <= clast; c++) {
        int kb = c * 128;
        __syncthreads();
#pragma unroll
        for (int i = 0; i < 4; i++) {
            int kloc = wave * 32 + i * 8 + ks_row;
            gl_lds16(qkv + (size_t)(krow0 + kb + kloc) * QKV_N + DIM + hh*64 + ks_g*8,
                     &Ks[(wave*32 + i*8) * 64]);
        }
#pragma unroll
        for (int i = 0; i < 4; i++) {
            int dloc = wave * 16 + i * 4 + vs_row;
            int jsrc = vs_j0 ^ (dloc & 7);
            gl_lds16(vbase + (size_t)dloc * NSEQ + kb + jsrc * 8,
                     &Vs[(wave*16 + i*4) * 128]);
        }
        __syncthreads();
        float4v s[8];
#pragma unroll
        for (int t = 0; t < 8; t++) {
            int krow = (t*16 + l15) * 64;
            short8 ka0 = *(const short8*)&Ks[krow + ((quad    ) ^ swz) * 8];
            short8 ka1 = *(const short8*)&Ks[krow + ((quad + 4) ^ swz) * 8];
            float4v st = {0.f, 0.f, 0.f, 0.f};
            st = __builtin_amdgcn_mfma_f32_16x16x32_bf16(ka0, bq0, st, 0, 0, 0);
            st = __builtin_amdgcn_mfma_f32_16x16x32_bf16(ka1, bq1, st, 0, 0, 0);
            int ck = kb + t*16 + quad*4;
#pragma unroll
            for (int r = 0; r < 4; r++)
                if (ck + r >= 512 && ck + r - 512 > qlocal) st[r] = -1e30f;
            s[t] = st;
        }
        float mc = -1e30f;
#pragma unroll
        for (int t = 0; t < 8; t++)
#pragma unroll
            for (int r = 0; r < 4; r++) mc = fmaxf(mc, s[t][r]);
        mc = fmaxf(mc, __shfl_xor(mc, 16));
        mc = fmaxf(mc, __shfl_xor(mc, 32));
        float mn = fmaxf(m_, mc);
        float alpha = __expf(m_ - mn);
        m_ = mn;
        float su = 0.f;
#pragma unroll
        for (int t = 0; t < 8; t++) {
            union { u16 h[4]; uint2 v; } pk;
#pragma unroll
            for (int r = 0; r < 4; r++) {
                float p = __expf(s[t][r] - mn);
                su += p;
                pk.h[r] = f2bf(p);
            }
            *(uint2*)&pt[l15][t*16 + quad*4] = pk.v;
        }
        su += __shfl_xor(su, 16);
        su += __shfl_xor(su, 32);
        l_ = l_ * alpha + su;
#pragma unroll
        for (int t = 0; t < 4; t++)
#pragma unroll
            for (int r = 0; r < 4; r++) O[t][r] *= alpha;
#pragma unroll
        for (int g = 0; g < 4; g++) {
            short8 pf = *(const short8*)&pt[l15][g*32 + quad*8];
#pragma unroll
            for (int t = 0; t < 4; t++) {
                short8 vf = *(const short8*)&Vs[(t*16 + l15) * 128 + ((g*4 + quad) ^ swz) * 8];
                O[t] = __builtin_amdgcn_mfma_f32_16x16x32_bf16(vf, pf, O[t], 0, 0, 0);
            }
        }
    }
    float inv = 1.f / l_;
    u16* op = o + (size_t)(b*NSEQ + w0*WIN + qt*16 + l15) * DIM + hh*64;
#pragma unroll
    for (int t = 0; t < 4; t++) {
        union { u16 h[4]; uint2 v; } pk;
#pragma unroll
        for (int r = 0; r < 4; r++) pk.h[r] = f2bf(O[t][r] * inv);
        *(uint2*)(op + t*16 + quad*4) = pk.v;
    }
}

// ---------------- launch ----------------
extern "C" void kernel_launch(void* const* d_in, const int* in_sizes, int n_in,
                              void* d_out, int out_size, void* d_ws, size_t ws_size,
                              hipStream_t stream) {
    const float* x      = (const float*)d_in[0];
    const float* ln1_w  = (const float*)d_in[1];
    const float* ln1_b  = (const float*)d_in[2];
    const float* w_qkv  = (const float*)d_in[3];
    const float* w_out  = (const float*)d_in[4];
    const float* ln2_w  = (const float*)d_in[5];
    const float* w_ff1  = (const float*)d_in[6];
    const float* w_ff2  = (const float*)d_in[7];
    float* out = (float*)d_out;

    char* ws = (char*)d_ws;
    size_t off = 0;
    auto alloc = [&](size_t bytes) { size_t o = off; off += (bytes + 255) & ~(size_t)255; return o; };
    size_t off_wqt  = alloc((size_t)QKV_N  * DIM * 2);
    size_t off_wot  = alloc((size_t)DIM    * DIM * 2);
    size_t off_wf1t = alloc((size_t)FF1_NP * DIM * 2);
    size_t off_wf2t = alloc((size_t)DIM    * INNER_P * 2);
    size_t off_h    = alloc((size_t)ROWS * DIM * 2);
    size_t sz_qkv = (size_t)ROWS * QKV_N * 2;
    size_t sz_vt  = (size_t)BATCH * HEADS * DH * NSEQ * 2;
    size_t off_qkv  = alloc(sz_qkv);
    size_t off_vt   = alloc(sz_vt);
    size_t off_o    = alloc((size_t)ROWS * DIM * 2);
    size_t off_x1   = alloc((size_t)ROWS * DIM * 4);
    size_t off_ag   = alloc((size_t)ROWS * INNER_P * 2);

    u16* wqt  = (u16*)(ws + off_wqt);
    u16* wot  = (u16*)(ws + off_wot);
    u16* wf1t = (u16*)(ws + off_wf1t);
    u16* wf2t = (u16*)(ws + off_wf2t);
    u16* h    = (u16*)(ws + off_h);
    u16* qkv  = (u16*)(ws + off_qkv);
    u16* vt   = (u16*)(ws + off_vt);
    u16* o    = (u16*)(ws + off_o);
    float* x1 = (float*)(ws + off_x1);
    u16* ag   = (u16*)(ws + off_ag);

    // 0) transpose+cast weights -> bf16 [N][K]; ff1 column-interleaved (a,g) pairs
    wtrans_kernel<false><<<dim3(32, 96),  256, 0, stream>>>(w_qkv, wqt,  DIM,   QKV_N, DIM,     QKV_N);
    wtrans_kernel<false><<<dim3(32, 32),  256, 0, stream>>>(w_out, wot,  DIM,   DIM,   DIM,     DIM);
    wtrans_kernel<true ><<<dim3(32, 172), 256, 0, stream>>>(w_ff1, wf1t, DIM,   FF1_N, DIM,     FF1_NP);
    wtrans_kernel<false><<<dim3(86, 32),  256, 0, stream>>>(w_ff2, wf2t, INNER, DIM,   INNER_P, DIM);

    // 1) LN1
    ln_kernel<<<ROWS, 256, 0, stream>>>(x, ln1_w, ln1_b, h);
    // 2) qkv = h @ w_qkv, rotary+scale fused in epilogue
    gemm_tile<2><<<(ROWS/128) * (QKV_N/128), 256, 0, stream>>>(h, wqt, nullptr, qkv, ROWS, QKV_N, DIM);
    // 3) V transpose
    vtrans_kernel<<<BATCH * HEADS * (NSEQ / 64), 256, 0, stream>>>(qkv, vt);
    // 4) attention
    attn_kernel<<<BATCH * HEADS * 8 * 8, 256, 0, stream>>>(qkv, vt, o);
    // 5) x1 = o @ w_out + x
    gemm_tile<1><<<(ROWS/128) * (DIM/128), 256, 0, stream>>>(o, wot, x, x1, ROWS, DIM, DIM);
    // 6) h2 = LN2(x1)
    ln_kernel<<<ROWS, 256, 0, stream>>>(x1, ln2_w, nullptr, h);
    // 7) ag = geglu(h2 @ w_ff1) fused (interleaved wf1t), writes [8192 x 2752]
    gemm_tile<3><<<(ROWS/128) * (FF1_NP/128), 256, 0, stream>>>(h, wf1t, nullptr, ag, ROWS, FF1_NP, DIM);
    // 8) out = ag @ w_ff2 + x1
    gemm_tile<1><<<(ROWS/128) * (DIM/128), 256, 0, stream>>>(ag, wf2t, x1, out, ROWS, DIM, INNER_P);

    (void)in_sizes; (void)n_in; (void)out_size; (void)ws_size;
}